// Round 1
// baseline (644.562 us; speedup 1.0000x reference)
//
#include <hip/hip_runtime.h>

#define TSTEPS 64
#define NI 8192
#define NO 8192
#define KS 16                 // K-split factor
#define KCH (NI / KS)         // 512 K per block
#define BK 16                 // K per LDS tile
#define NT (KCH / BK)         // 32 tiles
#define BO 512                // o per block
#define WST (BO + 4)          // padded LDS stride (bank-conflict-free)
#define DECAY 0.9375f

#define FMA4(A, Wv, s) \
    A.x += Wv.x * (s); A.y += Wv.y * (s); A.z += Wv.z * (s); A.w += Wv.w * (s);

// ---------------------------------------------------------------------------
// Kernel 0: detect whether the bool spike raster arrived as uint8 (1 B/elem)
// or int32 (4 B/elem). int32 layout has bytes 1..3 of every dword == 0;
// uint8 layout (20% density) is certain to have nonzero bytes there.
// ---------------------------------------------------------------------------
__global__ __launch_bounds__(256) void detect_kernel(const unsigned int* sp, int* flag) {
    __shared__ int any;
    if (threadIdx.x == 0) any = 0;
    __syncthreads();
    int local = 0;
    for (int i = threadIdx.x; i < (TSTEPS * NI) / 4; i += 256) {
        unsigned int w = sp[i];
        if (w & 0xFFFFFF00u) local = 1;
    }
    if (local) atomicOr(&any, 1);
    __syncthreads();
    if (threadIdx.x == 0) *flag = any;   // 1 => uint8 layout, 0 => int32 layout
}

// ---------------------------------------------------------------------------
// Kernel 1: convert spikes -> f32, transposed to [k][t] layout (2 MB in ws).
// Each block handles 64 k-columns, transposes through LDS so both global
// reads and writes are coalesced.
// ---------------------------------------------------------------------------
__global__ __launch_bounds__(256) void convert_kernel(const void* sp, const int* flag,
                                                      float* __restrict__ s_ws) {
    __shared__ float tile[64][65];
    const int b = blockIdx.x;           // k-range [b*64, b*64+64)
    const int f = *flag;
    for (int rep = 0; rep < 16; ++rep) {
        int idx = rep * 256 + threadIdx.x;   // 0..4095
        int t = idx >> 6, kl = idx & 63;
        int gidx = t * NI + b * 64 + kl;
        float v;
        if (f) v = ((const unsigned char*)sp)[gidx] ? 1.0f : 0.0f;
        else   v = ((const int*)sp)[gidx]           ? 1.0f : 0.0f;
        tile[kl][t] = v;
    }
    __syncthreads();
    for (int rep = 0; rep < 16; ++rep) {
        int idx = rep * 256 + threadIdx.x;
        int kl = idx >> 6, t = idx & 63;
        s_ws[(size_t)(b * 64 + kl) * TSTEPS + t] = tile[kl][t];
    }
}

// ---------------------------------------------------------------------------
// Kernel 2: skinny GEMM  partial[kb][t][o] = sum_{k in chunk kb} W[o][k]*S[k][t]
// 256 blocks (16 o-blocks x 16 K-splits), 256 threads (4 waves).
// Wave covers 128 o x 64 t; lane covers 16 o x 8 t (128 f32 accumulators).
// W staged transposed [k][o] in LDS (pad +4); o-fragment interleave og*4+32m
// makes frag reads bank-conflict-free. Double-buffered, 1 barrier/tile.
// ---------------------------------------------------------------------------
__global__ __launch_bounds__(256) void gemm_kernel(const float* __restrict__ W,
                                                   const float* __restrict__ s_ws,
                                                   float* __restrict__ partial) {
    __shared__ float Wl[2][BK][WST];
    __shared__ float Sl[2][BK][TSTEPS];

    const int tid  = threadIdx.x;
    const int ob   = blockIdx.x & 15;   // o-block (NO/BO = 16)
    const int kb   = blockIdx.x >> 4;   // K-split index
    const int w    = tid >> 6;          // wave 0..3
    const int lane = tid & 63;
    const int og   = lane & 7;
    const int tg   = lane >> 3;
    const int wbase = w * 128, og4 = og * 4, tg8 = tg * 8;
    const int a  = tid & 3;             // k-quad within tile
    const int rr = tid >> 2;            // staging row 0..63
    const int kstart = kb * KCH;

    float4 acc[4][8];
    #pragma unroll
    for (int m = 0; m < 4; ++m)
        #pragma unroll
        for (int i = 0; i < 8; ++i) acc[m][i] = make_float4(0.f, 0.f, 0.f, 0.f);

    float4 wr[8];
    float4 sr;

    auto load_tile = [&](int tt) {
        const int k0 = kstart + tt * BK;
        const float4* W4 = reinterpret_cast<const float4*>(W);
        #pragma unroll
        for (int p = 0; p < 8; ++p) {
            int o_loc = p * 64 + rr;
            wr[p] = W4[(size_t)(ob * BO + o_loc) * (NI / 4) + (k0 >> 2) + a];
        }
        sr = reinterpret_cast<const float4*>(s_ws)[((size_t)k0 * TSTEPS >> 2) + tid];
    };
    auto write_tile = [&](int buf) {
        #pragma unroll
        for (int p = 0; p < 8; ++p) {
            int o_loc = p * 64 + rr;
            Wl[buf][a * 4 + 0][o_loc] = wr[p].x;
            Wl[buf][a * 4 + 1][o_loc] = wr[p].y;
            Wl[buf][a * 4 + 2][o_loc] = wr[p].z;
            Wl[buf][a * 4 + 3][o_loc] = wr[p].w;
        }
        *reinterpret_cast<float4*>(&Sl[buf][tid >> 4][(tid & 15) * 4]) = sr;
    };

    load_tile(0);
    write_tile(0);
    __syncthreads();

    int cur = 0;
    for (int tt = 0; tt < NT; ++tt) {
        if (tt + 1 < NT) load_tile(tt + 1);   // global loads issue early
        #pragma unroll
        for (int k = 0; k < BK; ++k) {
            float4 wf0 = *reinterpret_cast<const float4*>(&Wl[cur][k][wbase + og4 + 0]);
            float4 wf1 = *reinterpret_cast<const float4*>(&Wl[cur][k][wbase + og4 + 32]);
            float4 wf2 = *reinterpret_cast<const float4*>(&Wl[cur][k][wbase + og4 + 64]);
            float4 wf3 = *reinterpret_cast<const float4*>(&Wl[cur][k][wbase + og4 + 96]);
            float4 s0  = *reinterpret_cast<const float4*>(&Sl[cur][k][tg8]);
            float4 s1  = *reinterpret_cast<const float4*>(&Sl[cur][k][tg8 + 4]);
            float sv[8] = {s0.x, s0.y, s0.z, s0.w, s1.x, s1.y, s1.z, s1.w};
            #pragma unroll
            for (int i = 0; i < 8; ++i) {
                FMA4(acc[0][i], wf0, sv[i]);
                FMA4(acc[1][i], wf1, sv[i]);
                FMA4(acc[2][i], wf2, sv[i]);
                FMA4(acc[3][i], wf3, sv[i]);
            }
        }
        if (tt + 1 < NT) write_tile(cur ^ 1); // waits vmcnt here, not before compute
        __syncthreads();
        cur ^= 1;
    }

    // epilogue: write partial sums
    #pragma unroll
    for (int i = 0; i < 8; ++i) {
        int t = tg8 + i;
        size_t base = (size_t)kb * TSTEPS * NO + (size_t)t * NO + ob * BO + wbase + og4;
        #pragma unroll
        for (int m = 0; m < 4; ++m)
            *reinterpret_cast<float4*>(&partial[base + 32 * m]) = acc[m][i];
    }
}

// ---------------------------------------------------------------------------
// Kernel 3: deterministic K-split reduction -> currents[t][o]
// ---------------------------------------------------------------------------
__global__ __launch_bounds__(256) void reduce_kernel(const float* __restrict__ partial,
                                                     float* __restrict__ currents) {
    int gid = blockIdx.x * 256 + threadIdx.x;   // over 64*8192
    float s = 0.f;
    #pragma unroll
    for (int kb = 0; kb < KS; ++kb) s += partial[(size_t)kb * TSTEPS * NO + gid];
    currents[gid] = s;
}

// ---------------------------------------------------------------------------
// Kernel 4: per-neuron LIF scan over 64 timesteps + output assembly.
// out = [spikes(65 x 8192) as f32 0/1, final mempot(8192)]
// ---------------------------------------------------------------------------
__global__ __launch_bounds__(256) void scan_kernel(const float* __restrict__ currents,
                                                   float* __restrict__ out) {
    int o = blockIdx.x * 256 + threadIdx.x;
    float m = 0.f;
    out[o] = 0.f;                                // spike row 0 stays zero
    for (int t = 0; t < TSTEPS; ++t) {
        m += currents[t * NO + o];
        bool sp = (m >= 1.0f);
        out[(size_t)(t + 1) * NO + o] = sp ? 1.0f : 0.0f;
        m = sp ? (m - 1.0f) : m * DECAY;
    }
    out[(size_t)(TSTEPS + 1) * NO + o] = m;      // final mempot
}

// ---------------------------------------------------------------------------
extern "C" void kernel_launch(void* const* d_in, const int* in_sizes, int n_in,
                              void* d_out, int out_size, void* d_ws, size_t ws_size,
                              hipStream_t stream) {
    const void*  spikes = d_in[0];
    const float* W      = (const float*)d_in[1];
    float*       out    = (float*)d_out;
    char*        ws     = (char*)d_ws;

    // ws layout: [flag 256 B][s_ws 2 MB][partial 32 MB][currents 2 MB] = ~36 MB
    int*   flag     = (int*)ws;
    float* s_ws     = (float*)(ws + 256);
    float* partial  = (float*)(ws + 256 + (size_t)NI * TSTEPS * 4);
    float* currents = (float*)(ws + 256 + (size_t)NI * TSTEPS * 4
                                        + (size_t)KS * TSTEPS * NO * 4);

    hipLaunchKernelGGL(detect_kernel,  dim3(1),                    dim3(256), 0, stream,
                       (const unsigned int*)spikes, flag);
    hipLaunchKernelGGL(convert_kernel, dim3(NI / 64),              dim3(256), 0, stream,
                       spikes, flag, s_ws);
    hipLaunchKernelGGL(gemm_kernel,    dim3(16 * KS),              dim3(256), 0, stream,
                       W, s_ws, partial);
    hipLaunchKernelGGL(reduce_kernel,  dim3(TSTEPS * NO / 256),    dim3(256), 0, stream,
                       partial, currents);
    hipLaunchKernelGGL(scan_kernel,    dim3(NO / 256),             dim3(256), 0, stream,
                       currents, out);
}

// Round 4
// 167.457 us; speedup vs baseline: 3.8491x; 3.8491x over previous
//
#include <hip/hip_runtime.h>

#define TSTEPS 64
#define NI 8192
#define NO 8192
#define KS 16                 // K-split factor
#define KCH (NI / KS)         // 512 k per block
#define NC (KCH / 32)         // 16 K=32 chunks per block
#define DECAY 0.9375f

typedef __attribute__((ext_vector_type(8))) short bf16x8;   // MFMA A/B frag (4 VGPR)
typedef __attribute__((ext_vector_type(4))) float f32x4;    // MFMA C/D frag

// ---------------------------------------------------------------------------
// Kernel 0 (verbatim round-1/3): detect uint8 vs int32 storage of the bool
// spike raster. Scans 512 KB (valid for both layouts).
// ---------------------------------------------------------------------------
__global__ __launch_bounds__(256) void detect_kernel(const unsigned int* sp, int* flag) {
    __shared__ int any;
    if (threadIdx.x == 0) any = 0;
    __syncthreads();
    int local = 0;
    for (int i = threadIdx.x; i < (TSTEPS * NI) / 4; i += 256) {
        unsigned int w = sp[i];
        if (w & 0xFFFFFF00u) local = 1;
    }
    if (local) atomicOr(&any, 1);
    __syncthreads();
    if (threadIdx.x == 0) *flag = any;   // 1 => uint8 layout, 0 => int32 layout
}

// ---------------------------------------------------------------------------
// Kernel 1 (verbatim round-3): spikes -> row-major bf16 S[t][k] (1 MB).
// ---------------------------------------------------------------------------
__global__ __launch_bounds__(256) void convert_kernel(const void* sp, const int* flag,
                                                      unsigned short* __restrict__ Sbf) {
    const int f = *flag;
    const int gid = blockIdx.x * 256 + threadIdx.x;   // 0..65535
    const int t   = gid >> 10;
    const int k0  = (gid & 1023) * 8;
    unsigned h[8];
    #pragma unroll
    for (int e = 0; e < 8; ++e) {
        int gi = t * NI + k0 + e;
        bool b;
        if (f) b = ((const unsigned char*)sp)[gi] != 0;
        else   b = ((const int*)sp)[gi] != 0;
        h[e] = b ? 0x3F80u : 0u;                      // bf16(1.0) = 0x3F80
    }
    uint4 v;
    v.x = h[0] | (h[1] << 16);
    v.y = h[2] | (h[3] << 16);
    v.z = h[4] | (h[5] << 16);
    v.w = h[6] | (h[7] << 16);
    *(uint4*)(Sbf + (size_t)t * NI + k0) = v;
}

// ---------------------------------------------------------------------------
// Triple split: w = hi + mid + lo.
//   hi  = trunc-bf16(w)        (w - hi exact: <=16-bit mantissa difference)
//   mid = trunc-bf16(w - hi)   (residual exact again)
//   lo  = RNE-bf16(w - hi - mid)
// Combined representation error <= 2^-22 |w| (~4e-9 per weight) — two orders
// below the spike-margin floor this test empirically tolerates.
// ---------------------------------------------------------------------------
__device__ __forceinline__ void split3(const float4& x, const float4& y,
                                       bf16x8& hi, bf16x8& mid, bf16x8& lo) {
    float v[8] = {x.x, x.y, x.z, x.w, y.x, y.y, y.z, y.w};
    #pragma unroll
    for (int e = 0; e < 8; ++e) {
        unsigned b   = __float_as_uint(v[e]);
        unsigned hb  = b & 0xFFFF0000u;
        float    r1  = v[e] - __uint_as_float(hb);                // exact
        unsigned r1b = __float_as_uint(r1);
        unsigned mb  = r1b & 0xFFFF0000u;
        float    r2  = r1 - __uint_as_float(mb);                  // exact
        unsigned r2b = __float_as_uint(r2);
        unsigned lr  = (r2b + 0x7FFFu + ((r2b >> 16) & 1u)) >> 16; // RNE bf16
        hi[e]  = (short)(b >> 16);
        mid[e] = (short)(mb >> 16);
        lo[e]  = (short)lr;
    }
}

// ---------------------------------------------------------------------------
// Kernel 2: skinny GEMM via triple-split bf16 MFMA. Structure identical to
// round 3 (which was layout-correct: failure was numeric); only the split
// and the 3rd MFMA per chunk changed.
// partial[kb][t][o] = sum_{k in chunk kb} W[o][k] * S[k][t]
// Grid: 32 o-blocks x 16 k-splits = 512 blocks x 256 threads (4 indep waves).
// ---------------------------------------------------------------------------
__global__ __launch_bounds__(256) void gemm_kernel(const float* __restrict__ W,
                                                   const unsigned short* __restrict__ Sbf,
                                                   float* __restrict__ partial) {
    const int lane = threadIdx.x & 63;
    const int w    = threadIdx.x >> 6;
    const int ob   = blockIdx.x & 31;
    const int kb   = blockIdx.x >> 5;
    const int r16  = lane & 15;
    const int kg   = lane >> 4;
    const int o0   = ob * 256 + w * 64;
    const int kbase = kb * KCH + kg * 8;

    f32x4 acc[4][4];
    #pragma unroll
    for (int m = 0; m < 4; ++m)
        #pragma unroll
        for (int n = 0; n < 4; ++n) acc[m][n] = (f32x4)0.f;

    #pragma unroll 2
    for (int c = 0; c < NC; ++c) {
        const int k = kbase + c * 32;
        bf16x8 Bf[4];
        #pragma unroll
        for (int n = 0; n < 4; ++n)
            Bf[n] = *(const bf16x8*)(Sbf + (size_t)(n * 16 + r16) * NI + k);
        #pragma unroll
        for (int m = 0; m < 4; ++m) {
            const float* ap = W + (size_t)(o0 + m * 16 + r16) * NI + k;
            float4 a0 = *(const float4*)ap;
            float4 a1 = *(const float4*)(ap + 4);
            bf16x8 hi, mid, lo;
            split3(a0, a1, hi, mid, lo);
            #pragma unroll
            for (int n = 0; n < 4; ++n) {
                acc[m][n] = __builtin_amdgcn_mfma_f32_16x16x32_bf16(
                    hi, Bf[n], acc[m][n], 0, 0, 0);
                acc[m][n] = __builtin_amdgcn_mfma_f32_16x16x32_bf16(
                    mid, Bf[n], acc[m][n], 0, 0, 0);
                acc[m][n] = __builtin_amdgcn_mfma_f32_16x16x32_bf16(
                    lo, Bf[n], acc[m][n], 0, 0, 0);
            }
        }
    }

    // Epilogue per verified D-map: t(col) = lane&15, o(row) = 4*kg + reg.
    #pragma unroll
    for (int m = 0; m < 4; ++m)
        #pragma unroll
        for (int n = 0; n < 4; ++n) {
            int t = n * 16 + r16;
            size_t off = (size_t)kb * TSTEPS * NO + (size_t)t * NO
                       + (o0 + m * 16 + kg * 4);
            *(f32x4*)&partial[off] = acc[m][n];
        }
}

// ---------------------------------------------------------------------------
// Kernel 3 (verbatim round-1): deterministic K-split reduction.
// ---------------------------------------------------------------------------
__global__ __launch_bounds__(256) void reduce_kernel(const float* __restrict__ partial,
                                                     float* __restrict__ currents) {
    int gid = blockIdx.x * 256 + threadIdx.x;   // over 64*8192
    float s = 0.f;
    #pragma unroll
    for (int kb = 0; kb < KS; ++kb) s += partial[(size_t)kb * TSTEPS * NO + gid];
    currents[gid] = s;
}

// ---------------------------------------------------------------------------
// Kernel 4 (verbatim round-1): per-neuron LIF scan.
// out = [spikes(65 x 8192) as f32 0/1, final mempot(8192)]
// ---------------------------------------------------------------------------
__global__ __launch_bounds__(256) void scan_kernel(const float* __restrict__ currents,
                                                   float* __restrict__ out) {
    int o = blockIdx.x * 256 + threadIdx.x;
    float m = 0.f;
    out[o] = 0.f;                                // spike row 0 stays zero
    for (int t = 0; t < TSTEPS; ++t) {
        m += currents[t * NO + o];
        bool sp = (m >= 1.0f);
        out[(size_t)(t + 1) * NO + o] = sp ? 1.0f : 0.0f;
        m = sp ? (m - 1.0f) : m * DECAY;
    }
    out[(size_t)(TSTEPS + 1) * NO + o] = m;      // final mempot
}

// ---------------------------------------------------------------------------
extern "C" void kernel_launch(void* const* d_in, const int* in_sizes, int n_in,
                              void* d_out, int out_size, void* d_ws, size_t ws_size,
                              hipStream_t stream) {
    const void*  spikes = d_in[0];
    const float* W      = (const float*)d_in[1];
    float*       out    = (float*)d_out;
    char*        ws     = (char*)d_ws;

    // ws layout: [flag 256 B][Sbf 1 MB][partial 32 MB][currents 2 MB] ~= 35.3 MB
    int*            flag     = (int*)ws;
    unsigned short* Sbf      = (unsigned short*)(ws + 256);
    float*          partial  = (float*)(ws + 256 + (size_t)1048576);
    float*          currents = (float*)(ws + 256 + (size_t)1048576
                                                 + (size_t)KS * TSTEPS * NO * 4);

    hipLaunchKernelGGL(detect_kernel,  dim3(1),                 dim3(256), 0, stream,
                       (const unsigned int*)spikes, flag);
    hipLaunchKernelGGL(convert_kernel, dim3(256),               dim3(256), 0, stream,
                       spikes, flag, Sbf);
    hipLaunchKernelGGL(gemm_kernel,    dim3(32 * KS),           dim3(256), 0, stream,
                       W, Sbf, partial);
    hipLaunchKernelGGL(reduce_kernel,  dim3(TSTEPS * NO / 256), dim3(256), 0, stream,
                       partial, currents);
    hipLaunchKernelGGL(scan_kernel,    dim3(NO / 256),          dim3(256), 0, stream,
                       currents, out);
}

// Round 5
// 100.065 us; speedup vs baseline: 6.4415x; 1.6735x over previous
//
#include <hip/hip_runtime.h>

#define TSTEPS 64
#define NI 8192
#define NO 8192
#define KS 16                 // K-split factor
#define KCH (NI / KS)         // 512 k per block
#define NC (KCH / 32)         // 16 K=32 chunks per block
#define DECAY 0.9375f
#define NDET 64               // detect blocks

typedef __attribute__((ext_vector_type(8))) short bf16x8;   // MFMA A/B frag (4 VGPR)
typedef __attribute__((ext_vector_type(4))) float f32x4;    // MFMA C/D frag

// ---------------------------------------------------------------------------
// Kernel 0: detect uint8 vs int32 storage of the bool spike raster.
// 64 blocks, each scans 8 KB of the first 512 KB (valid size for BOTH
// layouts) and writes its own flag word unconditionally — no serial block,
// no cross-block atomics. Consumer OR-reduces the 64 words.
// ---------------------------------------------------------------------------
__global__ __launch_bounds__(256) void detect_kernel(const unsigned int* sp, int* flags) {
    __shared__ int any;
    if (threadIdx.x == 0) any = 0;
    __syncthreads();
    int local = 0;
    const unsigned int* p = sp + blockIdx.x * 2048;       // 8 KB per block
    #pragma unroll
    for (int i = 0; i < 8; ++i) {
        unsigned int w = p[i * 256 + threadIdx.x];
        if (w & 0xFFFFFF00u) local = 1;
    }
    if (local) atomicOr(&any, 1);
    __syncthreads();
    if (threadIdx.x == 0) flags[blockIdx.x] = any;        // 1 => uint8 layout
}

// ---------------------------------------------------------------------------
// Kernel 1: spikes -> row-major bf16 S[t][k] (1 MB). 0/1 exact in bf16.
// ---------------------------------------------------------------------------
__global__ __launch_bounds__(256) void convert_kernel(const void* sp, const int* flags,
                                                      unsigned short* __restrict__ Sbf) {
    int f = 0;
    for (int i = 0; i < NDET; ++i) f |= flags[i];
    const int gid = blockIdx.x * 256 + threadIdx.x;   // 0..65535
    const int t   = gid >> 10;
    const int k0  = (gid & 1023) * 8;
    unsigned h[8];
    #pragma unroll
    for (int e = 0; e < 8; ++e) {
        int gi = t * NI + k0 + e;
        bool b;
        if (f) b = ((const unsigned char*)sp)[gi] != 0;
        else   b = ((const int*)sp)[gi] != 0;
        h[e] = b ? 0x3F80u : 0u;                      // bf16(1.0) = 0x3F80
    }
    uint4 v;
    v.x = h[0] | (h[1] << 16);
    v.y = h[2] | (h[3] << 16);
    v.z = h[4] | (h[5] << 16);
    v.w = h[6] | (h[7] << 16);
    *(uint4*)(Sbf + (size_t)t * NI + k0) = v;
}

// ---------------------------------------------------------------------------
// Triple split (UNCHANGED from round 4, which passed): w = hi + mid + lo,
// combined representation error <= 2^-22 |w|.
// ---------------------------------------------------------------------------
__device__ __forceinline__ void split3(const float4& x, const float4& y,
                                       bf16x8& hi, bf16x8& mid, bf16x8& lo) {
    float v[8] = {x.x, x.y, x.z, x.w, y.x, y.y, y.z, y.w};
    #pragma unroll
    for (int e = 0; e < 8; ++e) {
        unsigned b   = __float_as_uint(v[e]);
        unsigned hb  = b & 0xFFFF0000u;
        float    r1  = v[e] - __uint_as_float(hb);                // exact
        unsigned r1b = __float_as_uint(r1);
        unsigned mb  = r1b & 0xFFFF0000u;
        float    r2  = r1 - __uint_as_float(mb);                  // exact
        unsigned r2b = __float_as_uint(r2);
        unsigned lr  = (r2b + 0x7FFFu + ((r2b >> 16) & 1u)) >> 16; // RNE bf16
        hi[e]  = (short)(b >> 16);
        mid[e] = (short)(mb >> 16);
        lo[e]  = (short)lr;
    }
}

// ---------------------------------------------------------------------------
// Kernel 2: skinny GEMM via triple-split bf16 MFMA (numerics/maps unchanged
// from the passing round 4). Occupancy fix: wave tile halved to 32o x 64t,
// grid doubled to 64 ob x 16 kb = 1024 blocks (4/CU, 4 waves/SIMD),
// VGPR capped via __launch_bounds__(256,4). Base pointers hoisted so c-chunk
// offsets (<=2 KB) fold into load-immediate offsets.
// partial[kb][t][o] = sum_{k in chunk kb} W[o][k] * S[k][t]
// ---------------------------------------------------------------------------
__global__ __launch_bounds__(256, 4) void gemm_kernel(const float* __restrict__ W,
                                                      const unsigned short* __restrict__ Sbf,
                                                      float* __restrict__ partial) {
    const int lane = threadIdx.x & 63;
    const int w    = threadIdx.x >> 6;
    const int ob   = blockIdx.x & 63;   // 64 o-blocks of 128
    const int kb   = blockIdx.x >> 6;   // 16 k-splits
    const int r16  = lane & 15;
    const int kg   = lane >> 4;
    const int o0   = ob * 128 + w * 32;
    const int kbase = kb * KCH + kg * 8;

    f32x4 acc[2][4];
    #pragma unroll
    for (int m = 0; m < 2; ++m)
        #pragma unroll
        for (int n = 0; n < 4; ++n) acc[m][n] = (f32x4)0.f;

    const float* ap[2];
    #pragma unroll
    for (int m = 0; m < 2; ++m)
        ap[m] = W + (size_t)(o0 + m * 16 + r16) * NI + kbase;
    const unsigned short* bp[4];
    #pragma unroll
    for (int n = 0; n < 4; ++n)
        bp[n] = Sbf + (size_t)(n * 16 + r16) * NI + kbase;

    #pragma unroll 2
    for (int c = 0; c < NC; ++c) {
        bf16x8 Bf[4];
        #pragma unroll
        for (int n = 0; n < 4; ++n)
            Bf[n] = *(const bf16x8*)(bp[n] + c * 32);
        #pragma unroll
        for (int m = 0; m < 2; ++m) {
            float4 a0 = *(const float4*)(ap[m] + c * 32);
            float4 a1 = *(const float4*)(ap[m] + c * 32 + 4);
            bf16x8 hi, mid, lo;
            split3(a0, a1, hi, mid, lo);
            #pragma unroll
            for (int n = 0; n < 4; ++n) {
                acc[m][n] = __builtin_amdgcn_mfma_f32_16x16x32_bf16(
                    hi, Bf[n], acc[m][n], 0, 0, 0);
                acc[m][n] = __builtin_amdgcn_mfma_f32_16x16x32_bf16(
                    mid, Bf[n], acc[m][n], 0, 0, 0);
                acc[m][n] = __builtin_amdgcn_mfma_f32_16x16x32_bf16(
                    lo, Bf[n], acc[m][n], 0, 0, 0);
            }
        }
    }

    // Epilogue per verified D-map: t(col) = lane&15, o(row) = 4*kg + reg.
    #pragma unroll
    for (int m = 0; m < 2; ++m)
        #pragma unroll
        for (int n = 0; n < 4; ++n) {
            int t = n * 16 + r16;
            size_t off = (size_t)kb * TSTEPS * NO + (size_t)t * NO
                       + (o0 + m * 16 + kg * 4);
            *(f32x4*)&partial[off] = acc[m][n];
        }
}

// ---------------------------------------------------------------------------
// Kernel 3 (verbatim, passing): deterministic K-split reduction.
// ---------------------------------------------------------------------------
__global__ __launch_bounds__(256) void reduce_kernel(const float* __restrict__ partial,
                                                     float* __restrict__ currents) {
    int gid = blockIdx.x * 256 + threadIdx.x;   // over 64*8192
    float s = 0.f;
    #pragma unroll
    for (int kb = 0; kb < KS; ++kb) s += partial[(size_t)kb * TSTEPS * NO + gid];
    currents[gid] = s;
}

// ---------------------------------------------------------------------------
// Kernel 4 (verbatim, passing): per-neuron LIF scan.
// out = [spikes(65 x 8192) as f32 0/1, final mempot(8192)]
// ---------------------------------------------------------------------------
__global__ __launch_bounds__(256) void scan_kernel(const float* __restrict__ currents,
                                                   float* __restrict__ out) {
    int o = blockIdx.x * 256 + threadIdx.x;
    float m = 0.f;
    out[o] = 0.f;                                // spike row 0 stays zero
    for (int t = 0; t < TSTEPS; ++t) {
        m += currents[t * NO + o];
        bool sp = (m >= 1.0f);
        out[(size_t)(t + 1) * NO + o] = sp ? 1.0f : 0.0f;
        m = sp ? (m - 1.0f) : m * DECAY;
    }
    out[(size_t)(TSTEPS + 1) * NO + o] = m;      // final mempot
}

// ---------------------------------------------------------------------------
extern "C" void kernel_launch(void* const* d_in, const int* in_sizes, int n_in,
                              void* d_out, int out_size, void* d_ws, size_t ws_size,
                              hipStream_t stream) {
    const void*  spikes = d_in[0];
    const float* W      = (const float*)d_in[1];
    float*       out    = (float*)d_out;
    char*        ws     = (char*)d_ws;

    // ws layout: [flags 256 B][Sbf 1 MB][partial 32 MB][currents 2 MB] ~= 35.3 MB
    int*            flags    = (int*)ws;
    unsigned short* Sbf      = (unsigned short*)(ws + 256);
    float*          partial  = (float*)(ws + 256 + (size_t)1048576);
    float*          currents = (float*)(ws + 256 + (size_t)1048576
                                                 + (size_t)KS * TSTEPS * NO * 4);

    hipLaunchKernelGGL(detect_kernel,  dim3(NDET),              dim3(256), 0, stream,
                       (const unsigned int*)spikes, flags);
    hipLaunchKernelGGL(convert_kernel, dim3(256),               dim3(256), 0, stream,
                       spikes, flags, Sbf);
    hipLaunchKernelGGL(gemm_kernel,    dim3(64 * KS),           dim3(256), 0, stream,
                       W, Sbf, partial);
    hipLaunchKernelGGL(reduce_kernel,  dim3(TSTEPS * NO / 256), dim3(256), 0, stream,
                       partial, currents);
    hipLaunchKernelGGL(scan_kernel,    dim3(NO / 256),          dim3(256), 0, stream,
                       currents, out);
}